// Round 2
// baseline (364.451 us; speedup 1.0000x reference)
//
#include <hip/hip_runtime.h>
#include <cstdint>

#define IN_F 4096
#define OUT_F 11008
#define NG 32
#define BM 128
#define BN 64
#define BK 64
#define NKT 64
#define NBLK 688

typedef _Float16 half8 __attribute__((ext_vector_type(8)));
typedef _Float16 h2 __attribute__((ext_vector_type(2)));
typedef float f32x4 __attribute__((ext_vector_type(4)));

__device__ __forceinline__ int dq2(int u0, int u1, h2 sv, h2 bv) {
    // (q | 0x6400) as f16 = 1024+q exactly (q in [0,16)); subtract, then fma
    uint32_t t = ((uint32_t)u0 | ((uint32_t)u1 << 16)) | 0x64006400u;
    h2 v = __builtin_bit_cast(h2, t);
    v = v - (h2){(_Float16)1024.0f, (_Float16)1024.0f};
    v = v * sv + bv;
    return __builtin_bit_cast(int, v);
}

// nibble-packed: dword w holds 8 k-consecutive elems, pos i<4 = elem 2i,
// pos i+4 = elem 2i+1; ((w>>sh)&0x000F000F)|0x6400... -> adjacent f16 pair.
__device__ __forceinline__ int dqn(uint32_t w, int sh, h2 sv, h2 bv) {
    uint32_t t = ((w >> sh) & 0x000F000Fu) | 0x64006400u;
    h2 v = __builtin_bit_cast(h2, t);
    v = v - (h2){(_Float16)1024.0f, (_Float16)1024.0f};
    v = v * sv + bv;
    return __builtin_bit_cast(int, v);
}

// full B-fragment dequant: dword (8 nibbles) + packed {s_f16, (-z*s)_f16} dword
__device__ __forceinline__ half8 dqb(uint32_t w, uint32_t sz) {
    uint32_t svu = (sz & 0xFFFFu) | (sz << 16);       // {sh, sh}
    uint32_t bvu = (sz >> 16) | (sz & 0xFFFF0000u);   // {bh, bh}
    h2 sv = __builtin_bit_cast(h2, svu);
    h2 bv = __builtin_bit_cast(h2, bvu);
    int4 o;
    o.x = dqn(w, 0, sv, bv);
    o.y = dqn(w, 4, sv, bv);
    o.z = dqn(w, 8, sv, bv);
    o.w = dqn(w, 12, sv, bv);
    return __builtin_bit_cast(half8, o);
}

// ---------- prepass A: x fp32->f16 (blocks 0..1023) + scale/zp pack --------
// szp entry per (strip, g, lane): int4 of 4 dwords (nt=0..3), each dword =
// bits(s_f16) | bits((-z*s)_f16)<<16 for row = strip*64 + nt*16 + (lane&15).
// (quad-duplicated so the GEMM read is a single coalesced int4 per lane)
__global__ __launch_bounds__(256) void prep(const float* __restrict__ x,
                                            _Float16* __restrict__ xh,
                                            const float* __restrict__ sc,
                                            const float* __restrict__ zpt,
                                            uint32_t* __restrict__ szp) {
    const int b = blockIdx.x;
    if (b < 1024) {
        int i = (b * 256 + threadIdx.x) * 8;
        float4 f0 = *(const float4*)(x + i);
        float4 f1 = *(const float4*)(x + i + 4);
        int4 o;
        o.x = __builtin_bit_cast(int, __builtin_amdgcn_cvt_pkrtz(f0.x, f0.y));
        o.y = __builtin_bit_cast(int, __builtin_amdgcn_cvt_pkrtz(f0.z, f0.w));
        o.z = __builtin_bit_cast(int, __builtin_amdgcn_cvt_pkrtz(f1.x, f1.y));
        o.w = __builtin_bit_cast(int, __builtin_amdgcn_cvt_pkrtz(f1.z, f1.w));
        *(int4*)(xh + i) = o;
    } else {
        // 1376 blocks: 172 strips * 32 groups * 64 lanes entries
        int idx = (b - 1024) * 256 + threadIdx.x;
        int strip = idx >> 11;          // / 2048
        int rem   = idx & 2047;
        int g     = rem >> 6;
        int lane  = rem & 63;
        int l16v  = lane & 15;
        uint32_t d[4];
#pragma unroll
        for (int nt = 0; nt < 4; ++nt) {
            int orow = strip * 64 + nt * 16 + l16v;
            float s = sc[(size_t)orow * NG + g];
            float z = zpt[(size_t)orow * NG + g];
            _Float16 sh = (_Float16)s;
            _Float16 bh = (_Float16)(-z * s);
            d[nt] = (uint32_t)__builtin_bit_cast(unsigned short, sh)
                  | ((uint32_t)__builtin_bit_cast(unsigned short, bh) << 16);
        }
        int4 v; v.x = (int)d[0]; v.y = (int)d[1]; v.z = (int)d[2]; v.w = (int)d[3];
        *(int4*)(szp + (size_t)idx * 4) = v;
    }
}

// ---------- prepass B: q_weight int32 -> lane-direct nibble fragments ------
// pwT entry per (strip, kt, lane): 8 dwords. dword j (ks=j>>2, nt=j&3) packs
// qw[strip*64 + nt*16 + (lane&15)][kt*64 + ks*32 + (lane>>4)*8 .. +8].
// GEMM reads 2 int4/lane/K-tile, contiguous 2 KB per (strip,kt) -> coalesced.
__global__ __launch_bounds__(256) void pack_w2(const int* __restrict__ qw,
                                               uint32_t* __restrict__ pwT) {
    const int b = blockIdx.x;                 // 172*16 = 2752
    const int strip = b >> 4, kc = b & 15;
    const int t = threadIdx.x;
    const int kt = kc * 4 + (t >> 6);
    const int lane = t & 63;
    const int l16v = lane & 15, quad = lane >> 4;
    uint32_t d[8];
#pragma unroll
    for (int ks = 0; ks < 2; ++ks) {
#pragma unroll
        for (int nt = 0; nt < 4; ++nt) {
            const int row = strip * 64 + nt * 16 + l16v;
            const int kb  = kt * 64 + ks * 32 + quad * 8;
            const int4* p = (const int4*)(qw + (size_t)row * IN_F + kb);
            int4 q0 = p[0], q1 = p[1];
            // e0..e7 = q0.x q0.y q0.z q0.w q1.x q1.y q1.z q1.w (k-order)
            d[ks * 4 + nt] =
                  (uint32_t)q0.x | ((uint32_t)q0.z << 4)
                | ((uint32_t)q1.x << 8) | ((uint32_t)q1.z << 12)
                | ((uint32_t)q0.y << 16) | ((uint32_t)q0.w << 20)
                | ((uint32_t)q1.y << 24) | ((uint32_t)q1.w << 28);
        }
    }
    size_t base = ((size_t)(strip * 64 + kt) * 64 + lane) * 8;
    int4 v0; v0.x = (int)d[0]; v0.y = (int)d[1]; v0.z = (int)d[2]; v0.w = (int)d[3];
    int4 v1; v1.x = (int)d[4]; v1.y = (int)d[5]; v1.z = (int)d[6]; v1.w = (int)d[7];
    *(int4*)(pwT + base)     = v0;
    *(int4*)(pwT + base + 4) = v1;
}

// ---------- shared A-path macros -------------------------------------------
#define PF_A(kt) do {                                                          \
    const _Float16* _p = xh + (size_t)(m0 + rg) * IN_F + (kt) * BK + c8 * 8;   \
    aP0 = *(const int4*)(_p);                                                  \
    aP1 = *(const int4*)(_p + (size_t)32 * IN_F);                              \
    aP2 = *(const int4*)(_p + (size_t)64 * IN_F);                              \
    aP3 = *(const int4*)(_p + (size_t)96 * IN_F);                              \
} while (0)

#define STAGE_A(buf) do {                                                      \
    *(int4*)&As[buf][(rg)      * BK + xo] = aP0;                               \
    *(int4*)&As[buf][(rg + 32) * BK + xo] = aP1;                               \
    *(int4*)&As[buf][(rg + 64) * BK + xo] = aP2;                               \
    *(int4*)&As[buf][(rg + 96) * BK + xo] = aP3;                               \
} while (0)

// ---------- B-direct macros (mfma7) ----------------------------------------
#define PF_B2(kt, S) do {                                                      \
    size_t _o = ((size_t)(strip * 64 + (kt)) * 64 + lane) * 8;                 \
    (q##S##0) = *(const int4*)(pwT + _o);                                      \
    (q##S##1) = *(const int4*)(pwT + _o + 4);                                  \
    (sz##S)   = *(const int4*)(szp +                                           \
                  ((size_t)(strip * 32 + ((kt) >> 1)) * 64 + lane) * 4);       \
} while (0)

#define COMPUTE(buf, S) do {                                                   \
    {   const int _sw = ((quad ^ (l16 & 7)) << 3);                             \
        half8 _a0 = *(const half8*)&As[buf][(wm +      l16) * BK + _sw];       \
        half8 _a1 = *(const half8*)&As[buf][(wm + 16 + l16) * BK + _sw];       \
        half8 _b0 = dqb((uint32_t)(q##S##0).x, (uint32_t)(sz##S).x);           \
        half8 _b1 = dqb((uint32_t)(q##S##0).y, (uint32_t)(sz##S).y);           \
        half8 _b2 = dqb((uint32_t)(q##S##0).z, (uint32_t)(sz##S).z);           \
        half8 _b3 = dqb((uint32_t)(q##S##0).w, (uint32_t)(sz##S).w);           \
        acc[0][0] = __builtin_amdgcn_mfma_f32_16x16x32_f16(_a0, _b0, acc[0][0], 0, 0, 0); \
        acc[0][1] = __builtin_amdgcn_mfma_f32_16x16x32_f16(_a0, _b1, acc[0][1], 0, 0, 0); \
        acc[0][2] = __builtin_amdgcn_mfma_f32_16x16x32_f16(_a0, _b2, acc[0][2], 0, 0, 0); \
        acc[0][3] = __builtin_amdgcn_mfma_f32_16x16x32_f16(_a0, _b3, acc[0][3], 0, 0, 0); \
        acc[1][0] = __builtin_amdgcn_mfma_f32_16x16x32_f16(_a1, _b0, acc[1][0], 0, 0, 0); \
        acc[1][1] = __builtin_amdgcn_mfma_f32_16x16x32_f16(_a1, _b1, acc[1][1], 0, 0, 0); \
        acc[1][2] = __builtin_amdgcn_mfma_f32_16x16x32_f16(_a1, _b2, acc[1][2], 0, 0, 0); \
        acc[1][3] = __builtin_amdgcn_mfma_f32_16x16x32_f16(_a1, _b3, acc[1][3], 0, 0, 0); \
    }                                                                          \
    {   const int _sw = (((4 + quad) ^ (l16 & 7)) << 3);                       \
        half8 _a0 = *(const half8*)&As[buf][(wm +      l16) * BK + _sw];       \
        half8 _a1 = *(const half8*)&As[buf][(wm + 16 + l16) * BK + _sw];       \
        half8 _b0 = dqb((uint32_t)(q##S##1).x, (uint32_t)(sz##S).x);           \
        half8 _b1 = dqb((uint32_t)(q##S##1).y, (uint32_t)(sz##S).y);           \
        half8 _b2 = dqb((uint32_t)(q##S##1).z, (uint32_t)(sz##S).z);           \
        half8 _b3 = dqb((uint32_t)(q##S##1).w, (uint32_t)(sz##S).w);           \
        acc[0][0] = __builtin_amdgcn_mfma_f32_16x16x32_f16(_a0, _b0, acc[0][0], 0, 0, 0); \
        acc[0][1] = __builtin_amdgcn_mfma_f32_16x16x32_f16(_a0, _b1, acc[0][1], 0, 0, 0); \
        acc[0][2] = __builtin_amdgcn_mfma_f32_16x16x32_f16(_a0, _b2, acc[0][2], 0, 0, 0); \
        acc[0][3] = __builtin_amdgcn_mfma_f32_16x16x32_f16(_a0, _b3, acc[0][3], 0, 0, 0); \
        acc[1][0] = __builtin_amdgcn_mfma_f32_16x16x32_f16(_a1, _b0, acc[1][0], 0, 0, 0); \
        acc[1][1] = __builtin_amdgcn_mfma_f32_16x16x32_f16(_a1, _b1, acc[1][1], 0, 0, 0); \
        acc[1][2] = __builtin_amdgcn_mfma_f32_16x16x32_f16(_a1, _b2, acc[1][2], 0, 0, 0); \
        acc[1][3] = __builtin_amdgcn_mfma_f32_16x16x32_f16(_a1, _b3, acc[1][3], 0, 0, 0); \
    }                                                                          \
} while (0)

// ---------- main GEMM v7: B fully in registers, A via LDS ------------------
// Wave w owns rows wm=w*32..+31 (mt=0,1) x all 64 cols (nt=0..3): A rows are
// disjoint per wave (no LDS read dup), B frags lane-direct from pwT (no B LDS).
// LDS traffic/block-tile: 72 KB (mfma6) -> 32 KB; binding floor moves to MFMA.
__global__ __launch_bounds__(256, 3) void qlin_mfma7(
    const _Float16* __restrict__ xh, const uint32_t* __restrict__ pwT,
    const uint32_t* __restrict__ szp, const float* __restrict__ bias,
    float* __restrict__ out)
{
    __shared__ __align__(16) _Float16 As[2][BM * BK]; // 2 x 16 KB

    const int tid = threadIdx.x;
    // XCD-colocation swizzle (proven: FETCH 936->219->175 MB)
    int L = blockIdx.x, strip, mblk;
    if (L < 672) { int p = L >> 5, i = L & 31; strip = p * 8 + (i & 7); mblk = i >> 3; }
    else         { int i = L - 672;            strip = 168 + (i & 3);   mblk = i >> 2; }
    const int m0 = mblk * BM;
    const int n0 = strip * BN;

    const int lane = tid & 63;
    const int w    = tid >> 6;
    const int wm   = w * 32;
    const int l16  = lane & 15;
    const int quad = lane >> 4;

    const int c8 = tid & 7;               // A: 16B granule within 64-elem row
    const int rg = tid >> 3;              // A: 0..31
    const int xo = (c8 ^ (rg & 7)) << 3;  // A: XOR-swizzled slot

    int4 aP0, aP1, aP2, aP3;              // A f16 prefetch (dist-1)
    int4 qA0, qA1, szA;                   // B set A (dist-2)
    int4 qB0, qB1, szB;                   // B set B (dist-2)

    f32x4 acc[2][4];
#pragma unroll
    for (int mt = 0; mt < 2; ++mt)
#pragma unroll
        for (int nt = 0; nt < 4; ++nt)
            acc[mt][nt] = (f32x4){0.f, 0.f, 0.f, 0.f};

    // prologue
    PF_B2(0, A);
    PF_A(0);
    PF_B2(1, B);
    STAGE_A(0);
    PF_A(1);
    __syncthreads();

#pragma unroll 1
    for (int kt = 0; kt < NKT; kt += 2) {
        // even tile kt: stage A(kt+1), prefetch A(kt+2); compute set A; refill A
        STAGE_A(1);
        { int ka = kt + 2 < NKT ? kt + 2 : NKT - 1; PF_A(ka); }
        COMPUTE(0, A);
        { int kb = kt + 2 < NKT ? kt + 2 : NKT - 1; PF_B2(kb, A); }
        __syncthreads();
        // odd tile kt+1
        if (kt + 2 < NKT) {
            STAGE_A(0);
            int ka = kt + 3 < NKT ? kt + 3 : NKT - 1;
            PF_A(ka);
        }
        COMPUTE(1, B);
        { int kb = kt + 3 < NKT ? kt + 3 : NKT - 1; PF_B2(kb, B); }
        __syncthreads();
    }

    // epilogue: C/D layout col = l16 (n), row = quad*4 + r (m)
#pragma unroll
    for (int nt = 0; nt < 4; ++nt) {
        int n = n0 + nt * 16 + l16;
        float bv = bias[n];
#pragma unroll
        for (int mt = 0; mt < 2; ++mt) {
            int mb = m0 + wm + mt * 16 + quad * 4;
#pragma unroll
            for (int r = 0; r < 4; ++r)
                out[(size_t)(mb + r) * OUT_F + n] = acc[mt][nt][r] + bv;
        }
    }
}

// ---------- fallback kernels (proven) --------------------------------------
__global__ __launch_bounds__(256) void cvt_x(const float* __restrict__ x,
                                             _Float16* __restrict__ xh) {
    int i = (blockIdx.x * 256 + threadIdx.x) * 8;
    float4 f0 = *(const float4*)(x + i);
    float4 f1 = *(const float4*)(x + i + 4);
    int4 o;
    o.x = __builtin_bit_cast(int, __builtin_amdgcn_cvt_pkrtz(f0.x, f0.y));
    o.y = __builtin_bit_cast(int, __builtin_amdgcn_cvt_pkrtz(f0.z, f0.w));
    o.z = __builtin_bit_cast(int, __builtin_amdgcn_cvt_pkrtz(f1.x, f1.y));
    o.w = __builtin_bit_cast(int, __builtin_amdgcn_cvt_pkrtz(f1.z, f1.w));
    *(int4*)(xh + i) = o;
}

#define PF_B(kt, S) do {                                                       \
    const int _k0 = (kt) * BK; const int _g = (kt) >> 1;                       \
    const int* _p0 = qw + (size_t)(n0 + rg) * IN_F + _k0 + c8 * 8;             \
    (q##S##0) = *(const int4*)(_p0);                                           \
    (q##S##1) = *(const int4*)(_p0 + 4);                                       \
    (q##S##2) = *(const int4*)(_p0 + (size_t)32 * IN_F);                       \
    (q##S##3) = *(const int4*)(_p0 + (size_t)32 * IN_F + 4);                   \
    (s##S##0) = sc [(size_t)(n0 + rg) * NG + _g];                              \
    (s##S##1) = sc [(size_t)(n0 + rg + 32) * NG + _g];                         \
    (z##S##0) = zpt[(size_t)(n0 + rg) * NG + _g];                              \
    (z##S##1) = zpt[(size_t)(n0 + rg + 32) * NG + _g];                         \
} while (0)

#define STAGE_B(buf, S) do {                                                   \
    float _s0 = (s##S##0); _Float16 _h0 = (_Float16)_s0;                       \
    _Float16 _b0 = (_Float16)(-(z##S##0) * _s0);                               \
    h2 _sv0 = {_h0, _h0}, _bv0 = {_b0, _b0};                                   \
    int4 _o;                                                                   \
    _o.x = dq2((q##S##0).x, (q##S##0).y, _sv0, _bv0);                          \
    _o.y = dq2((q##S##0).z, (q##S##0).w, _sv0, _bv0);                          \
    _o.z = dq2((q##S##1).x, (q##S##1).y, _sv0, _bv0);                          \
    _o.w = dq2((q##S##1).z, (q##S##1).w, _sv0, _bv0);                          \
    *(int4*)&Bs[buf][(rg) * BK + xo] = _o;                                     \
    float _s1 = (s##S##1); _Float16 _h1 = (_Float16)_s1;                       \
    _Float16 _b1 = (_Float16)(-(z##S##1) * _s1);                               \
    h2 _sv1 = {_h1, _h1}, _bv1 = {_b1, _b1};                                   \
    _o.x = dq2((q##S##2).x, (q##S##2).y, _sv1, _bv1);                          \
    _o.y = dq2((q##S##2).z, (q##S##2).w, _sv1, _bv1);                          \
    _o.z = dq2((q##S##3).x, (q##S##3).y, _sv1, _bv1);                          \
    _o.w = dq2((q##S##3).z, (q##S##3).w, _sv1, _bv1);                          \
    *(int4*)&Bs[buf][(rg + 32) * BK + xo] = _o;                                \
} while (0)

__global__ __launch_bounds__(256, 3) void qlin_mfma5(
    const _Float16* __restrict__ xh, const int* __restrict__ qw,
    const float* __restrict__ sc, const float* __restrict__ zpt,
    const float* __restrict__ bias, float* __restrict__ out)
{
    __shared__ __align__(16) _Float16 As[2][BM * BK];
    __shared__ __align__(16) _Float16 Bs[2][BN * BK];

    const int tid = threadIdx.x;
    int L = blockIdx.x, strip, mblk;
    if (L < 672) { int p = L >> 5, i = L & 31; strip = p * 8 + (i & 7); mblk = i >> 3; }
    else         { int i = L - 672;            strip = 168 + (i & 3);   mblk = i >> 2; }
    const int m0 = mblk * BM;
    const int n0 = strip * BN;

    const int lane = tid & 63;
    const int w    = tid >> 6;
    const int wm   = (w & 1) * 64;
    const int wn   = (w >> 1) * 32;
    const int l16  = lane & 15;
    const int quad = lane >> 4;

    const int c8 = tid & 7;
    const int rg = tid >> 3;
    const int xo = (c8 ^ (rg & 7)) << 3;

    int4 aP0, aP1, aP2, aP3;
    int4 qA0, qA1, qA2, qA3; float sA0, sA1, zA0, zA1;
    int4 qB0, qB1, qB2, qB3; float sB0, sB1, zB0, zB1;

    f32x4 acc[4][2];
#pragma unroll
    for (int mt = 0; mt < 4; ++mt)
#pragma unroll
        for (int nt = 0; nt < 2; ++nt)
            acc[mt][nt] = (f32x4){0.f, 0.f, 0.f, 0.f};

    auto compute = [&](int buf) {
#pragma unroll
        for (int ks = 0; ks < 2; ++ks) {
            half8 a[4], b[2];
            const int ck = ks * 4 + quad;
#pragma unroll
            for (int mt = 0; mt < 4; ++mt) {
                int row = wm + mt * 16 + l16;
                a[mt] = *(const half8*)&As[buf][row * BK + ((ck ^ (row & 7)) << 3)];
            }
#pragma unroll
            for (int nt = 0; nt < 2; ++nt) {
                int row = wn + nt * 16 + l16;
                b[nt] = *(const half8*)&Bs[buf][row * BK + ((ck ^ (row & 7)) << 3)];
            }
#pragma unroll
            for (int mt = 0; mt < 4; ++mt)
#pragma unroll
                for (int nt = 0; nt < 2; ++nt)
                    acc[mt][nt] = __builtin_amdgcn_mfma_f32_16x16x32_f16(
                        a[mt], b[nt], acc[mt][nt], 0, 0, 0);
        }
    };

    PF_B(0, A);
    PF_A(0);
    PF_B(1, B);
    STAGE_A(0);
    STAGE_B(0, A);
    PF_A(1);
    PF_B(2, A);
    __syncthreads();

#pragma unroll 1
    for (int kt = 0; kt < NKT; kt += 2) {
        {
            STAGE_A(1);
            STAGE_B(1, B);
            int ka = kt + 2 < NKT ? kt + 2 : NKT - 1;
            int kb = kt + 3 < NKT ? kt + 3 : NKT - 1;
            PF_A(ka);
            PF_B(kb, B);
        }
        compute(0);
        __syncthreads();
        if (kt + 2 < NKT) {
            STAGE_A(0);
            STAGE_B(0, A);
            int ka = kt + 3 < NKT ? kt + 3 : NKT - 1;
            int kb = kt + 4 < NKT ? kt + 4 : NKT - 1;
            PF_A(ka);
            PF_B(kb, A);
        }
        compute(1);
        __syncthreads();
    }

#pragma unroll
    for (int nt = 0; nt < 2; ++nt) {
        int n = n0 + wn + nt * 16 + l16;
        float bv = bias[n];
#pragma unroll
        for (int mt = 0; mt < 4; ++mt) {
            int mb = m0 + wm + mt * 16 + quad * 4;
#pragma unroll
            for (int r = 0; r < 4; ++r)
                out[(size_t)(mb + r) * OUT_F + n] = acc[mt][nt][r] + bv;
        }
    }
}

__global__ __launch_bounds__(256, 3) void qlin_mfma4(
    const float* __restrict__ x, const int* __restrict__ qw,
    const float* __restrict__ sc, const float* __restrict__ zpt,
    const float* __restrict__ bias, float* __restrict__ out)
{
    __shared__ __align__(16) _Float16 As[2][BM * BK];
    __shared__ __align__(16) _Float16 Bs[2][BN * BK];

    const int tid = threadIdx.x;
    int L = blockIdx.x, strip, mblk;
    if (L < 672) { int p = L >> 5, i = L & 31; strip = p * 8 + (i & 7); mblk = i >> 3; }
    else         { int i = L - 672;            strip = 168 + (i & 3);   mblk = i >> 2; }
    const int m0 = mblk * BM;
    const int n0 = strip * BN;

    const int lane = tid & 63;
    const int w    = tid >> 6;
    const int wm   = (w & 1) * 64;
    const int wn   = (w >> 1) * 32;
    const int l16  = lane & 15;
    const int quad = lane >> 4;

    const int c8 = tid & 7;
    const int rg = tid >> 3;

    float4 aP[8];
    int4   bP[4];
    float  sP[2], zP[2];

    auto pf = [&](int kt) {
        const int k0 = kt * BK;
        const int g  = kt >> 1;
#pragma unroll
        for (int j = 0; j < 4; ++j) {
            int row = rg + 32 * j;
            const float4* p = (const float4*)(x + (size_t)(m0 + row) * IN_F + k0 + c8 * 8);
            aP[2 * j]     = p[0];
            aP[2 * j + 1] = p[1];
        }
#pragma unroll
        for (int j = 0; j < 2; ++j) {
            int row = n0 + rg + 32 * j;
            const int4* p = (const int4*)(qw + (size_t)row * IN_F + k0 + c8 * 8);
            bP[2 * j]     = p[0];
            bP[2 * j + 1] = p[1];
            sP[j] = sc [(size_t)row * NG + g];
            zP[j] = zpt[(size_t)row * NG + g];
        }
    };

    auto stage = [&](int buf) {
#pragma unroll
        for (int j = 0; j < 4; ++j) {
            int row = rg + 32 * j;
            float4 f0 = aP[2 * j], f1 = aP[2 * j + 1];
            int4 o;
            o.x = __builtin_bit_cast(int, __builtin_amdgcn_cvt_pkrtz(f0.x, f0.y));
            o.y = __builtin_bit_cast(int, __builtin_amdgcn_cvt_pkrtz(f0.z, f0.w));
            o.z = __builtin_bit_cast(int, __builtin_amdgcn_cvt_pkrtz(f1.x, f1.y));
            o.w = __builtin_bit_cast(int, __builtin_amdgcn_cvt_pkrtz(f1.z, f1.w));
            *(int4*)&As[buf][row * BK + ((c8 ^ (row & 7)) << 3)] = o;
        }
#pragma unroll
        for (int j = 0; j < 2; ++j) {
            int row = rg + 32 * j;
            float sf = sP[j];
            _Float16 sh = (_Float16)sf;
            _Float16 bh = (_Float16)(-zP[j] * sf);
            h2 sv = {sh, sh}, bv = {bh, bh};
            int4 q0 = bP[2 * j], q1 = bP[2 * j + 1];
            int4 o;
            o.x = dq2(q0.x, q0.y, sv, bv);
            o.y = dq2(q0.z, q0.w, sv, bv);
            o.z = dq2(q1.x, q1.y, sv, bv);
            o.w = dq2(q1.z, q1.w, sv, bv);
            *(int4*)&Bs[buf][row * BK + ((c8 ^ (row & 7)) << 3)] = o;
        }
    };

    f32x4 acc[4][2];
#pragma unroll
    for (int mt = 0; mt < 4; ++mt)
#pragma unroll
        for (int nt = 0; nt < 2; ++nt)
            acc[mt][nt] = (f32x4){0.f, 0.f, 0.f, 0.f};

    auto compute = [&](int buf) {
#pragma unroll
        for (int ks = 0; ks < 2; ++ks) {
            half8 a[4], b[2];
            const int ck = ks * 4 + quad;
#pragma unroll
            for (int mt = 0; mt < 4; ++mt) {
                int row = wm + mt * 16 + l16;
                a[mt] = *(const half8*)&As[buf][row * BK + ((ck ^ (row & 7)) << 3)];
            }
#pragma unroll
            for (int nt = 0; nt < 2; ++nt) {
                int row = wn + nt * 16 + l16;
                b[nt] = *(const half8*)&Bs[buf][row * BK + ((ck ^ (row & 7)) << 3)];
            }
#pragma unroll
            for (int mt = 0; mt < 4; ++mt)
#pragma unroll
                for (int nt = 0; nt < 2; ++nt)
                    acc[mt][nt] = __builtin_amdgcn_mfma_f32_16x16x32_f16(
                        a[mt], b[nt], acc[mt][nt], 0, 0, 0);
        }
    };

    pf(0);
    stage(0);
    __syncthreads();

#pragma unroll 1
    for (int kt = 0; kt < NKT; ++kt) {
        const int buf = kt & 1;
        if (kt + 1 < NKT) {
            pf(kt + 1);
            compute(buf);
            stage(buf ^ 1);
            __syncthreads();
        } else {
            compute(buf);
        }
    }

#pragma unroll
    for (int nt = 0; nt < 2; ++nt) {
        int n = n0 + wn + nt * 16 + l16;
        float bv = bias[n];
#pragma unroll
        for (int mt = 0; mt < 4; ++mt) {
            int mb = m0 + wm + mt * 16 + quad * 4;
#pragma unroll
            for (int r = 0; r < 4; ++r)
                out[(size_t)(mb + r) * OUT_F + n] = acc[mt][nt][r] + bv;
        }
    }
}

extern "C" void kernel_launch(void* const* d_in, const int* in_sizes, int n_in,
                              void* d_out, int out_size, void* d_ws, size_t ws_size,
                              hipStream_t stream) {
    const float* x    = (const float*)d_in[0];
    const int*   qw   = (const int*)d_in[1];
    const float* scp  = (const float*)d_in[2];
    const float* zpp  = (const float*)d_in[3];
    const float* bias = (const float*)d_in[4];
    float* out = (float*)d_out;
    (void)in_sizes; (void)n_in; (void)out_size;

    const size_t XH_BYTES = (size_t)512 * IN_F * sizeof(_Float16);     // 4 MB
    const size_t PW_BYTES = (size_t)OUT_F * IN_F / 2;                  // 22.5 MB
    const size_t SZ_BYTES = (size_t)172 * 32 * 64 * 16;                // 5.6 MB

    if (ws_size >= XH_BYTES + PW_BYTES + SZ_BYTES) {
        _Float16* xh  = (_Float16*)d_ws;
        uint32_t* pwT = (uint32_t*)((char*)d_ws + XH_BYTES);
        uint32_t* szp = (uint32_t*)((char*)d_ws + XH_BYTES + PW_BYTES);
        prep   <<<dim3(2400), dim3(256), 0, stream>>>(x, xh, scp, zpp, szp);
        pack_w2<<<dim3(2752), dim3(256), 0, stream>>>(qw, pwT);
        qlin_mfma7<<<dim3(NBLK), dim3(256), 0, stream>>>(xh, pwT, szp, bias, out);
    } else if (ws_size >= XH_BYTES) {
        _Float16* xh = (_Float16*)d_ws;
        cvt_x<<<dim3(1024), dim3(256), 0, stream>>>(x, xh);
        qlin_mfma5<<<dim3(NBLK), dim3(256), 0, stream>>>(xh, qw, scp, zpp, bias, out);
    } else {
        qlin_mfma4<<<dim3(NBLK), dim3(256), 0, stream>>>(x, qw, scp, zpp, bias, out);
    }
}